// Round 7
// baseline (319.641 us; speedup 1.0000x reference)
//
#include <hip/hip_runtime.h>
#include <math.h>

#define TPB 256

typedef __attribute__((ext_vector_type(8))) short s16x8;
typedef __attribute__((ext_vector_type(4))) float f32x4;
typedef unsigned int u32;

constexpr int Bn = 64, Kc = 24, TSz = 11;
constexpr int NBK = Bn * Kc;          // 1536
constexpr int CH = 768;               // (b,k) instances per chunk
constexpr int NCHUNK = NBK / CH;      // 2
constexpr int P1 = 361, P2 = 81, P3 = 49, P4 = 25;

// ---- workspace offsets (BYTES) ----
constexpr size_t SZW_B    = (size_t)Kc * 36 * 4096 * 2;      // 7,077,888 B/plane
constexpr size_t OFFB_W2  = 0;
constexpr size_t OFFB_W3  = OFFB_W2 + SZW_B;
constexpr size_t OFFB_W4  = OFFB_W3 + SZW_B;
constexpr size_t OFFB_H1  = OFFB_W4 + SZW_B;
constexpr size_t OFFB_H2  = OFFB_H1 + (size_t)CH * P1 * 128 * 2;
constexpr size_t OFFB_H3  = OFFB_H2 + (size_t)CH * P2 * 128 * 2;
constexpr size_t OFFB_H4  = OFFB_H3 + (size_t)CH * P3 * 128 * 2;
constexpr size_t OFFB_POSE= OFFB_H4 + (size_t)CH * P4 * 128 * 2;
constexpr size_t OFFB_DMV = OFFB_POSE + (size_t)NBK * 6 * 4;
constexpr size_t OFFB_TT  = OFFB_DMV + (size_t)NBK * 4;
constexpr size_t OFFB_ST  = OFFB_TT + (size_t)NBK * 1600 * 4;
constexpr size_t OFFB_MXS = OFFB_ST + 512;
constexpr size_t OFFB_PART= OFFB_MXS + (size_t)NBK * 2 * 4;

// ---- output offsets (floats) ----
constexpr int OUT_OC = 1;                   // input_ocae [B,K,136]
constexpr int OUT_XM = 1 + NBK * 136;
constexpr int OUT_DM = OUT_XM + NBK * 6;

// ============ bf16 helpers ============
__device__ __forceinline__ ushort f2b(float f) {
    union { float f; unsigned u; } c; c.f = f;
    unsigned r = c.u + 0x7fffu + ((c.u >> 16) & 1u);
    return (ushort)(r >> 16);
}
__device__ __forceinline__ float b2f(ushort h) {
    union { unsigned u; float f; } c; c.u = ((unsigned)h) << 16; return c.f;
}

// ============ reductions (TPB=256 → 4 waves) ============
__device__ __forceinline__ float blockReduceSum(float v) {
    __shared__ float red[4];
    __syncthreads();
#pragma unroll
    for (int o = 32; o > 0; o >>= 1) v += __shfl_down(v, o, 64);
    int lane = threadIdx.x & 63, wv = threadIdx.x >> 6;
    if (lane == 0) red[wv] = v;
    __syncthreads();
    return red[0] + red[1] + red[2] + red[3];
}

__device__ __forceinline__ float blockReduceMax(float v) {
    __shared__ float redm[4];
    __syncthreads();
#pragma unroll
    for (int o = 32; o > 0; o >>= 1) v = fmaxf(v, __shfl_down(v, o, 64));
    int lane = threadIdx.x & 63, wv = threadIdx.x >> 6;
    if (lane == 0) redm[wv] = v;
    __syncthreads();
    return fmaxf(fmaxf(redm[0], redm[1]), fmaxf(redm[2], redm[3]));
}

// ============ weight prep: w[k][cout][cin][tap] f32 -> bf16 frag-major ============
// dst: [k][cb][tap] blocks of 4096 ush, inner [n][g][l16][e]  (n=cout/16, l16=cout%16,
// g=c32/8, e=c32%8) — 1 KB contiguous per (n) fragment = perfectly coalesced wave load.
__global__ __launch_bounds__(128) void wprep_k(const float* __restrict__ w,
                                               ushort* __restrict__ wt) {
    __shared__ float ld[1152];
    const int k = blockIdx.x >> 7, cout = blockIdx.x & 127;
    const float* src = w + (size_t)(k * 128 + cout) * 1152;
    for (int i = threadIdx.x; i < 1152; i += 128) ld[i] = src[i];
    __syncthreads();
    const int n = cout >> 4, l16 = cout & 15;
    for (int e = threadIdx.x; e < 1152; e += 128) {
        int cb = e / 288, r = e - cb * 288, tap = r >> 5, c32 = r & 31;
        int cin = cb * 32 + c32;
        size_t d = (size_t)((k * 4 + cb) * 9 + tap) * 4096
                 + n * 512 + (c32 >> 3) * 128 + l16 * 8 + (c32 & 7);
        wt[d] = f2b(ld[cin * 9 + tap]);
    }
}

// ============ conv1: block per (b,k); x in LDS, weights in VGPRs ============
__global__ __launch_bounds__(TPB) void conv1_k(const float* __restrict__ x,
                                               const float* __restrict__ w1,
                                               const float* __restrict__ b1,
                                               ushort* __restrict__ h1, int bk0) {
    __shared__ float xs[1600];
    const int bkL = blockIdx.x;
    const int bk = bk0 + bkL;
    const int b = bk / Kc, k = bk - b * Kc;
    for (int i = threadIdx.x; i < 400; i += TPB)
        ((f32x4*)xs)[i] = ((const f32x4*)(x + b * 1600))[i];
    const int c8 = (threadIdx.x & 15) * 8;
    const int pg = threadIdx.x >> 4;         // 0..15
    float wr[72];
    const float* wp = w1 + (size_t)(k * 128 + c8) * 9;
#pragma unroll
    for (int j = 0; j < 18; ++j) ((f32x4*)wr)[j] = ((const f32x4*)wp)[j];
    float bias8[8];
#pragma unroll
    for (int j = 0; j < 8; ++j) bias8[j] = b1[k * 128 + c8 + j];
    __syncthreads();
    ushort* hb = h1 + (size_t)bkL * 361 * 128 + c8;
    for (int p = pg; p < 361; p += 16) {
        int py = p / 19, px = p - py * 19;
        const float* xb = xs + py * 80 + px * 2;
        float xt[9];
#pragma unroll
        for (int dy = 0; dy < 3; ++dy)
#pragma unroll
            for (int dx = 0; dx < 3; ++dx) xt[dy * 3 + dx] = xb[dy * 40 + dx];
        s16x8 v;
#pragma unroll
        for (int j = 0; j < 8; ++j) {
            float s = bias8[j];
#pragma unroll
            for (int t9 = 0; t9 < 9; ++t9) s += wr[j * 9 + t9] * xt[t9];
            v[j] = (short)f2b(fmaxf(s, 0.f));
        }
        *(s16x8*)(hb + (size_t)p * 128) = v;
    }
}

// ============ MFMA implicit-GEMM conv (one (b,k) per block) ============
// 4 waves = 2 m-groups x 2 n-groups; wave = MW m-frags x 4 n-frags.
// As rows stride 44 ushorts (bank-spread: reads/writes <=2-3 way, no XOR needed).
// A staged per 32-cin slab via batched issue-early register staging (T14):
// all loads in flight together -> ONE HBM latency per cb, issued before tap-8 MFMAs.
// B (weights) 3-deep per-wave register prefetch (it%3, compile-time via full unroll):
// ~2 tap-periods + ds_write drain to cover L2 latency; loads survive barriers.
template <int IH, int IW, int OH, int OW, int ST, int MW>
__global__ __launch_bounds__(256) void mfconv_k(
    const ushort* __restrict__ hin, const ushort* __restrict__ wt,
    const float* __restrict__ bias, ushort* __restrict__ hout) {
    constexpr int IP = IH * IW, OP = OH * OW;
    constexpr int STR = 44;                       // LDS row stride (ushorts)
    constexpr int NLD = (IP * 4 + 255) / 256;     // staging chunks per thread
    __shared__ ushort As[IP * STR];
    const int bi = blockIdx.x;
    const int xcd = bi & 7, j = bi >> 3;
    const int k = xcd * 3 + j % 3, grp = j / 3;   // k-clustered per XCD
    const int bkL = grp * 24 + k;                 // 0..767
    const int tid = threadIdx.x;
    const int w = tid >> 6, l = tid & 63, l16 = l & 15, g = l >> 4;
    const int mgrp = w >> 1, ngrp = w & 1;
    const ushort* hsrc = hin + (size_t)bkL * IP * 128;
    const ushort* wb = wt + (size_t)k * 36 * 4096 + ngrp * 2048 + g * 128 + l16 * 8;

    f32x4 acc[MW][4];
#pragma unroll
    for (int m = 0; m < MW; ++m)
#pragma unroll
        for (int n = 0; n < 4; ++n) acc[m][n] = (f32x4)0.f;

    int ibase[MW];
#pragma unroll
    for (int m = 0; m < MW; ++m) {
        int row = (mgrp * MW + m) * 16 + l16;
        row = row < OP ? row : OP - 1;
        int oy = row / OW, ox = row - oy * OW;
        ibase[m] = oy * ST * IW + ox * ST;
    }

    s16x8 rv[NLD];
    bool rva[NLD];
    int rrow[NLD], rgc[NLD];
#pragma unroll
    for (int i = 0; i < NLD; ++i) {
        int t = tid + i * 256;
        rva[i] = t < IP * 4;
        int tc = rva[i] ? t : 0;
        rrow[i] = tc >> 2; rgc[i] = tc & 3;
    }
    // prologue: stage cb=0 loads + first two B tap-slabs
#pragma unroll
    for (int i = 0; i < NLD; ++i)
        if (rva[i]) rv[i] = *(const s16x8*)(hsrc + (size_t)rrow[i] * 128 + rgc[i] * 8);
    s16x8 breg[3][4];
#pragma unroll
    for (int n = 0; n < 4; ++n) breg[0][n] = *(const s16x8*)(wb + n * 512);
#pragma unroll
    for (int n = 0; n < 4; ++n) breg[1][n] = *(const s16x8*)(wb + 4096 + n * 512);

#pragma unroll
    for (int cb = 0; cb < 4; ++cb) {
        // write staged regs to LDS (waits the batched loads once), sync
#pragma unroll
        for (int i = 0; i < NLD; ++i)
            if (rva[i]) *(s16x8*)(As + rrow[i] * STR + rgc[i] * 8) = rv[i];
        __syncthreads();
#pragma unroll
        for (int tap = 0; tap < 9; ++tap) {
            const int it = cb * 9 + tap;          // compile-time
            if (it + 2 < 36) {                    // 3-deep B prefetch
                const ushort* src = wb + (size_t)(it + 2) * 4096;
#pragma unroll
                for (int n = 0; n < 4; ++n)
                    breg[(it + 2) % 3][n] = *(const s16x8*)(src + n * 512);
            }
            if (tap == 8 && cb < 3) {             // issue next cb's A loads early
#pragma unroll
                for (int i = 0; i < NLD; ++i)
                    if (rva[i]) rv[i] = *(const s16x8*)(hsrc + (size_t)rrow[i] * 128 + (cb + 1) * 32 + rgc[i] * 8);
            }
            const int ioff = (tap / 3) * IW + (tap % 3);
            s16x8 a[MW];
#pragma unroll
            for (int m = 0; m < MW; ++m)
                a[m] = *(const s16x8*)(As + (ibase[m] + ioff) * STR + g * 8);
#pragma unroll
            for (int n = 0; n < 4; ++n) {
#pragma unroll
                for (int m = 0; m < MW; ++m)
                    acc[m][n] = __builtin_amdgcn_mfma_f32_16x16x32_bf16(a[m], breg[it % 3][n], acc[m][n], 0, 0, 0);
            }
        }
        __syncthreads();                          // As reads done before overwrite
    }
    // epilogue: C/D map col=lane&15, row=(lane>>4)*4+r
#pragma unroll
    for (int n = 0; n < 4; ++n) {
        int cout = (ngrp * 4 + n) * 16 + l16;
        float bv = bias[k * 128 + cout];
#pragma unroll
        for (int m = 0; m < MW; ++m) {
#pragma unroll
            for (int r = 0; r < 4; ++r) {
                int row = (mgrp * MW + m) * 16 + g * 4 + r;
                if (row < OP) {
                    float v2 = fmaxf(acc[m][n][r] + bv, 0.f);
                    hout[((size_t)bkL * OP + row) * 128 + cout] = f2b(v2);
                }
            }
        }
    }
}

// ============ conv5 (1x1) + attention + pooling + heads + ocae assembly ============
__global__ __launch_bounds__(TPB) void head_k(const ushort* __restrict__ h4,
                                              const float* __restrict__ w5,
                                              const float* __restrict__ b5,
                                              const float* __restrict__ tpl,
                                              float* __restrict__ pose,
                                              float* __restrict__ dmv,
                                              float* __restrict__ out, int bk0) {
    __shared__ float h4s[128 * 25];   // [c][pix]
    __shared__ float outs[16 * 25];   // [f][pix]
    __shared__ float atts[25];
    __shared__ float pooled[16];
    const int bk = bk0 + blockIdx.x;
    const int k = bk % Kc;
    const ushort* hb = h4 + (size_t)blockIdx.x * 25 * 128;
    for (int i = threadIdx.x; i < 25 * 128; i += TPB) {
        int pix = i >> 7, c = i & 127;
        h4s[c * 25 + pix] = b2f(hb[i]);
    }
    __syncthreads();
    for (int t = threadIdx.x; t < 400; t += TPB) {
        int f = t / 25, pix = t - f * 25;
        const float* wp = w5 + (size_t)(k * 16 + f) * 128;
        float s = b5[k * 16 + f];
        for (int c = 0; c < 128; ++c) s += wp[c] * h4s[c * 25 + pix];
        outs[t] = s;
    }
    __syncthreads();
    if (threadIdx.x < 25) {
        int y5 = threadIdx.x / 5;
        const float* row = outs + 15 * 25 + y5 * 5;
        float mx = row[0];
#pragma unroll
        for (int j = 1; j < 5; ++j) mx = fmaxf(mx, row[j]);
        float ssum = 0.f;
#pragma unroll
        for (int j = 0; j < 5; ++j) ssum += expf(row[j] - mx);
        atts[threadIdx.x] = expf(outs[15 * 25 + threadIdx.x] - mx) / ssum;
    }
    __syncthreads();
    if (threadIdx.x < 15) {
        float s = 0.f;
        const float* row = outs + threadIdx.x * 25;
#pragma unroll
        for (int p = 0; p < 25; ++p) s += row[p] * atts[p];
        pooled[threadIdx.x] = s;
    }
    __syncthreads();
    float* oc = out + OUT_OC + (size_t)bk * 136;
    if (threadIdx.x < 6) {
        float v = fmaxf(pooled[threadIdx.x], 0.f);
        pose[bk * 6 + threadIdx.x] = v;
        oc[1 + threadIdx.x] = v;
        out[OUT_XM + bk * 6 + threadIdx.x] = v;
    } else if (threadIdx.x == 6) {
        float d = 1.f / (1.f + expf(-pooled[6]));
        dmv[bk] = d;
        oc[0] = d;
        out[OUT_DM + bk] = d;
    } else if (threadIdx.x >= 7 && threadIdx.x < 15) {
        oc[128 + threadIdx.x - 7] = fmaxf(pooled[threadIdx.x], 0.f);
    }
    for (int t = threadIdx.x; t < 121; t += TPB) oc[7 + t] = tpl[k * 121 + t];
}

// ============ affine warp + bilinear TS->40x40, fused mix-softmax stats ============
__device__ __forceinline__ float tapf(const float* tp, int y, int x) {
    bool valid = (x >= 0) && (x < TSz) && (y >= 0) && (y < TSz);
    int yc = min(max(y, 0), TSz - 1), xc = min(max(x, 0), TSz - 1);
    float v = tp[yc * TSz + xc];
    return valid ? v : 0.f;
}

__global__ __launch_bounds__(TPB) void warp_mix_k(const float* __restrict__ pose,
                                                  const float* __restrict__ tpl,
                                                  const float* __restrict__ dmv,
                                                  float* __restrict__ tt,
                                                  float* __restrict__ mxs) {
    __shared__ float tp[121];
    const int bk = blockIdx.x, k = bk % Kc;
    for (int i = threadIdx.x; i < 121; i += TPB) tp[i] = tpl[k * 121 + i];
    const float* ps = pose + bk * 6;
    const float D2R = 0.017453292519943295f;
    float ang = ps[0] * D2R, tx = ps[1], ty = ps[2];
    float sc = fmaxf(ps[3], 1e-2f);
    float shx = ps[4] * D2R, shy = ps[5] * D2R;
    float cams = cosf(ang - shy), sams = sinf(ang - shy);
    float cshy = cosf(shy), tshx = tanf(shx);
    float av = cams / cshy;
    float bv = -cams * tshx / cshy - sinf(ang);
    float cv = sams / cshy;
    float dv = -sams * tshx / cshy + cosf(ang);
    float m0 = dv / sc, m1 = -bv / sc, m3 = -cv / sc, m4 = av / sc;
    float m2 = m0 * (-5.f - tx) + m1 * (-5.f - ty) + 5.f;
    float m5 = m3 * (-5.f - tx) + m4 * (-5.f - ty) + 5.f;
    __syncthreads();
    float* to = tt + (size_t)bk * 1600;
    float tvl[7];
#pragma unroll
    for (int r = 0; r < 7; ++r) {
        int p = threadIdx.x + r * TPB;
        float val = 0.f;
        if (p < 1600) {
            int i = p / 40, jx = p - (p / 40) * 40;
            float gx = (jx + 0.5f) * (11.f / 40.f) - 0.5f;
            float gy = (i + 0.5f) * (11.f / 40.f) - 0.5f;
            float xin = m0 * gx + m1 * gy + m2;
            float yin = m3 * gx + m4 * gy + m5;
            float x0 = floorf(xin), y0 = floorf(yin);
            float wx = xin - x0, wy = yin - y0;
            int x0i = (int)x0, y0i = (int)y0;
            float v00 = tapf(tp, y0i, x0i),     v01 = tapf(tp, y0i, x0i + 1);
            float v10 = tapf(tp, y0i + 1, x0i), v11 = tapf(tp, y0i + 1, x0i + 1);
            val = v00 * (1.f - wx) * (1.f - wy) + v01 * wx * (1.f - wy) +
                  v10 * (1.f - wx) * wy + v11 * wx * wy;
            to[p] = val;
        }
        tvl[r] = val;
    }
    const float dm = dmv[bk];
    float mx = -1e30f;
#pragma unroll
    for (int r = 0; r < 7; ++r) {
        int p = threadIdx.x + r * TPB;
        if (p < 1600) mx = fmaxf(mx, dm * tvl[r]);
    }
    mx = blockReduceMax(mx);
    float s = 0.f;
#pragma unroll
    for (int r = 0; r < 7; ++r) {
        int p = threadIdx.x + r * TPB;
        if (p < 1600) s += expf(dm * tvl[r] - mx);
    }
    s = blockReduceSum(s);
    if (threadIdx.x == 0) { mxs[bk * 2] = mx; mxs[bk * 2 + 1] = s; }
}

// ============ per-sample std stats ============
__global__ __launch_bounds__(TPB) void std_k(const float* __restrict__ x,
                                             float* __restrict__ st) {
    const int b = blockIdx.x;
    const float* xb = x + b * 1600;
    float s = 0.f, s2 = 0.f;
    for (int p = threadIdx.x; p < 1600; p += TPB) {
        float v = xb[p];
        s += v; s2 += v * v;
    }
    s = blockReduceSum(s);
    s2 = blockReduceSum(s2);
    if (threadIdx.x == 0) {
        float mean = s / 1600.f;
        float var = (s2 - 1600.f * mean * mean) / 1599.f;
        float sd = sqrtf(var);
        st[b * 2] = rsqrtf(sd * 6.283185307179586f);   // mult
        st[b * 2 + 1] = -1.f / (2.f * sd * sd);        // pw
    }
}

// ============ log-likelihood, split over 8 pixel-blocks per sample ============
__global__ __launch_bounds__(TPB) void ll_k(const float* __restrict__ x,
                                            const float* __restrict__ tt,
                                            const float* __restrict__ dmv,
                                            const float* __restrict__ mxs,
                                            const float* __restrict__ st,
                                            float* __restrict__ part) {
    const int b = blockIdx.x, sp = blockIdx.y;
    __shared__ float dms[24], mxh[24], sih[24];
    if (threadIdx.x < 24) {
        int bk = b * 24 + threadIdx.x;
        dms[threadIdx.x] = dmv[bk];
        mxh[threadIdx.x] = mxs[bk * 2];
        sih[threadIdx.x] = 1.f / mxs[bk * 2 + 1];
    }
    __syncthreads();
    const float mult = st[b * 2], pw = st[b * 2 + 1];
    const float* xb = x + b * 1600;
    const float* tb = tt + (size_t)b * 24 * 1600;
    float acc = 0.f;
    int p = sp * 200 + threadIdx.x;
    if (threadIdx.x < 200) {
        float xv = xb[p];
        float ssum = 0.f;
        for (int k = 0; k < 24; ++k) {
            float tv = tb[(size_t)k * 1600 + p];
            float dd = xv - tv;
            float g = mult * expf(dd * dd * pw);
            float mixv = expf(dms[k] * tv - mxh[k]) * sih[k];
            ssum += g * mixv;
        }
        acc = logf(ssum);
    }
    acc = blockReduceSum(acc);
    if (threadIdx.x == 0) part[b * 8 + sp] = acc;
}

__global__ void fin_k(const float* __restrict__ part, float* __restrict__ out) {
    float v = 0.f;
#pragma unroll
    for (int q = 0; q < 8; ++q) v += part[threadIdx.x * 8 + q];
#pragma unroll
    for (int o = 32; o > 0; o >>= 1) v += __shfl_down(v, o, 64);
    if (threadIdx.x == 0) out[0] = v * (1.f / 64.f);
}

// ============ launch ============
extern "C" void kernel_launch(void* const* d_in, const int* in_sizes, int n_in,
                              void* d_out, int out_size, void* d_ws, size_t ws_size,
                              hipStream_t stream) {
    const float* x   = (const float*)d_in[0];
    const float* w1  = (const float*)d_in[1];
    const float* b1  = (const float*)d_in[2];
    const float* w2  = (const float*)d_in[3];
    const float* b2  = (const float*)d_in[4];
    const float* w3  = (const float*)d_in[5];
    const float* b3  = (const float*)d_in[6];
    const float* w4  = (const float*)d_in[7];
    const float* b4  = (const float*)d_in[8];
    const float* w5  = (const float*)d_in[9];
    const float* b5  = (const float*)d_in[10];
    const float* tpl = (const float*)d_in[11];
    float* out = (float*)d_out;
    char* W = (char*)d_ws;

    ushort* wt2 = (ushort*)(W + OFFB_W2);
    ushort* wt3 = (ushort*)(W + OFFB_W3);
    ushort* wt4 = (ushort*)(W + OFFB_W4);
    ushort* h1u = (ushort*)(W + OFFB_H1);
    ushort* h2u = (ushort*)(W + OFFB_H2);
    ushort* h3u = (ushort*)(W + OFFB_H3);
    ushort* h4u = (ushort*)(W + OFFB_H4);
    float*  pose = (float*)(W + OFFB_POSE);
    float*  dmv  = (float*)(W + OFFB_DMV);
    float*  ttb  = (float*)(W + OFFB_TT);
    float*  stv  = (float*)(W + OFFB_ST);
    float*  mxs  = (float*)(W + OFFB_MXS);
    float*  part = (float*)(W + OFFB_PART);

    wprep_k<<<Kc * 128, 128, 0, stream>>>(w2, wt2);
    wprep_k<<<Kc * 128, 128, 0, stream>>>(w3, wt3);
    wprep_k<<<Kc * 128, 128, 0, stream>>>(w4, wt4);
    std_k<<<Bn, TPB, 0, stream>>>(x, stv);

    for (int ch = 0; ch < NCHUNK; ++ch) {
        int bk0 = ch * CH;
        conv1_k<<<CH, TPB, 0, stream>>>(x, w1, b1, h1u, bk0);
        mfconv_k<19, 19, 9, 9, 2, 3><<<768, 256, 0, stream>>>(h1u, wt2, b2, h2u);
        mfconv_k<9, 9, 7, 7, 1, 2><<<768, 256, 0, stream>>>(h2u, wt3, b3, h3u);
        mfconv_k<7, 7, 5, 5, 1, 1><<<768, 256, 0, stream>>>(h3u, wt4, b4, h4u);
        head_k<<<CH, TPB, 0, stream>>>(h4u, w5, b5, tpl, pose, dmv, out, bk0);
    }

    warp_mix_k<<<NBK, TPB, 0, stream>>>(pose, tpl, dmv, ttb, mxs);
    ll_k<<<dim3(Bn, 8), TPB, 0, stream>>>(x, ttb, dmv, mxs, stv, part);
    fin_k<<<1, 64, 0, stream>>>(part, out);
}

// Round 8
// 263.873 us; speedup vs baseline: 1.2113x; 1.2113x over previous
//
#include <hip/hip_runtime.h>
#include <math.h>

#define TPB 256

typedef __attribute__((ext_vector_type(8))) short s16x8;
typedef __attribute__((ext_vector_type(4))) short s16x4;
typedef __attribute__((ext_vector_type(4))) float f32x4;
typedef unsigned int u32;

constexpr int Bn = 64, Kc = 24, TSz = 11;
constexpr int NBK = Bn * Kc;          // 1536
constexpr int P2 = 81, P3 = 49, P4 = 25;

// ---- workspace offsets (BYTES) ----
constexpr size_t SZW_B    = (size_t)Kc * 36 * 4096 * 2;      // 7,077,888 B/plane
constexpr size_t OFFB_W2  = 0;
constexpr size_t OFFB_W3  = OFFB_W2 + SZW_B;
constexpr size_t OFFB_W4  = OFFB_W3 + SZW_B;
constexpr size_t OFFB_H2  = OFFB_W4 + SZW_B;
constexpr size_t OFFB_H3  = OFFB_H2 + (size_t)NBK * P2 * 128 * 2;
constexpr size_t OFFB_H4  = OFFB_H3 + (size_t)NBK * P3 * 128 * 2;
constexpr size_t OFFB_POSE= OFFB_H4 + (size_t)NBK * P4 * 128 * 2;
constexpr size_t OFFB_DMV = OFFB_POSE + (size_t)NBK * 6 * 4;
constexpr size_t OFFB_TT  = OFFB_DMV + (size_t)NBK * 4;
constexpr size_t OFFB_ST  = OFFB_TT + (size_t)NBK * 1600 * 4;
constexpr size_t OFFB_MXS = OFFB_ST + 512;
constexpr size_t OFFB_PART= OFFB_MXS + (size_t)NBK * 2 * 4;

// ---- output offsets (floats) ----
constexpr int OUT_OC = 1;                   // input_ocae [B,K,136]
constexpr int OUT_XM = 1 + NBK * 136;
constexpr int OUT_DM = OUT_XM + NBK * 6;

// ============ bf16 helpers ============
__device__ __forceinline__ ushort f2b(float f) {
    union { float f; unsigned u; } c; c.f = f;
    unsigned r = c.u + 0x7fffu + ((c.u >> 16) & 1u);
    return (ushort)(r >> 16);
}
__device__ __forceinline__ float b2f(ushort h) {
    union { unsigned u; float f; } c; c.u = ((unsigned)h) << 16; return c.f;
}

// ============ reductions (TPB=256 → 4 waves) ============
__device__ __forceinline__ float blockReduceSum(float v) {
    __shared__ float red[4];
    __syncthreads();
#pragma unroll
    for (int o = 32; o > 0; o >>= 1) v += __shfl_down(v, o, 64);
    int lane = threadIdx.x & 63, wv = threadIdx.x >> 6;
    if (lane == 0) red[wv] = v;
    __syncthreads();
    return red[0] + red[1] + red[2] + red[3];
}

__device__ __forceinline__ float blockReduceMax(float v) {
    __shared__ float redm[4];
    __syncthreads();
#pragma unroll
    for (int o = 32; o > 0; o >>= 1) v = fmaxf(v, __shfl_down(v, o, 64));
    int lane = threadIdx.x & 63, wv = threadIdx.x >> 6;
    if (lane == 0) redm[wv] = v;
    __syncthreads();
    return fmaxf(fmaxf(redm[0], redm[1]), fmaxf(redm[2], redm[3]));
}

// ============ weight prep: w[k][cout][cin][tap] f32 -> bf16 frag-major ============
// dst: [k][cb][tap] blocks of 4096 ush, inner [n][g][l16][e] — 1 KB contiguous per
// (n) fragment = perfectly coalesced wave load.
__global__ __launch_bounds__(128) void wprep_k(const float* __restrict__ w,
                                               ushort* __restrict__ wt) {
    __shared__ float ld[1152];
    const int k = blockIdx.x >> 7, cout = blockIdx.x & 127;
    const float* src = w + (size_t)(k * 128 + cout) * 1152;
    for (int i = threadIdx.x; i < 1152; i += 128) ld[i] = src[i];
    __syncthreads();
    const int n = cout >> 4, l16 = cout & 15;
    for (int e = threadIdx.x; e < 1152; e += 128) {
        int cb = e / 288, r = e - cb * 288, tap = r >> 5, c32 = r & 31;
        int cin = cb * 32 + c32;
        size_t d = (size_t)((k * 4 + cb) * 9 + tap) * 4096
                 + n * 512 + (c32 >> 3) * 128 + l16 * 8 + (c32 & 7);
        wt[d] = f2b(ld[cin * 9 + tap]);
    }
}

// ============ FUSED conv1+conv2: one (b,k) per block ============
// conv1 (f32 VALU) computes each 32-cin slab of h1 on the fly into a double-buffered
// LDS A-slab (bf16-rounded, identical numerics to materialized h1); conv2's MFMA taps
// consume the other buffer. h1 NEVER touches HBM. One barrier per cb slab.
// 4 waves = 2 m-groups x 2 n-groups; wave = 3 m-frags x 4 n-frags (M=81 exact).
// A-slab rows stride 40 ushorts + octet XOR swizzle (round-5 proven, 16B-aligned).
// B (weights) 3-deep per-wave register ring (prefetch it+2), loads survive barriers.
__global__ __launch_bounds__(256) void conv12_k(
    const float* __restrict__ x, const float* __restrict__ w1,
    const float* __restrict__ b1, const ushort* __restrict__ wt,
    const float* __restrict__ bias, ushort* __restrict__ hout) {
    constexpr int IP = 361, OP = 81, STR = 40;
    __shared__ float xs[1600];
    __shared__ ushort As[2][IP * STR];          // 2 x 28,880 B
    const int bi = blockIdx.x;
    const int xcd = bi & 7, jj = bi >> 3;
    const int k = xcd * 3 + jj % 3, b = jj / 3;  // k-clustered per XCD
    const int bkL = b * 24 + k;
    const int tid = threadIdx.x;
    const int w = tid >> 6, l = tid & 63, l16 = l & 15, g = l >> 4;
    const int mgrp = w >> 1, ngrp = w & 1;
    const int sl = tid & 7, p0 = tid >> 3;       // conv1: cout-slice(4) x pixel stride 32
    const ushort* wb = wt + (size_t)k * 36 * 4096 + ngrp * 2048 + g * 128 + l16 * 8;
    const float* w1k = w1 + (size_t)k * 1152;
    const float* b1k = b1 + k * 128;

    // x -> LDS (2 f32x4 per thread)
    for (int i = tid; i < 400; i += 256)
        ((f32x4*)xs)[i] = ((const f32x4*)(x + b * 1600))[i];

    // B ring prologue: slabs 0,1
    s16x8 breg[3][4];
#pragma unroll
    for (int n = 0; n < 4; ++n) breg[0][n] = *(const s16x8*)(wb + n * 512);
#pragma unroll
    for (int n = 0; n < 4; ++n) breg[1][n] = *(const s16x8*)(wb + 4096 + n * 512);

    f32x4 acc[3][4];
#pragma unroll
    for (int m = 0; m < 3; ++m)
#pragma unroll
        for (int n = 0; n < 4; ++n) acc[m][n] = (f32x4)0.f;

    int ibase[3];
#pragma unroll
    for (int m = 0; m < 3; ++m) {
        int row = (mgrp * 3 + m) * 16 + l16;
        row = row < OP ? row : OP - 1;
        int oy = row / 9, ox = row - oy * 9;
        ibase[m] = oy * 38 + ox * 2;            // stride-2 input pixel
    }

    // conv1 slab writer: computes h1[cin = cb*32 + sl*4 .. +3] for pixels p0,p0+32,...
    float wq[36], bq[4];
    auto conv1_slab = [&](ushort* dA) {
        for (int p = p0; p < 361; p += 32) {
            int py = p / 19, px = p - py * 19;
            const float* xb = xs + py * 80 + px * 2;
            float xt[9];
#pragma unroll
            for (int dy = 0; dy < 3; ++dy)
#pragma unroll
                for (int dx = 0; dx < 3; ++dx) xt[dy * 3 + dx] = xb[dy * 40 + dx];
            s16x4 v;
#pragma unroll
            for (int j2 = 0; j2 < 4; ++j2) {
                float s2 = bq[j2];
#pragma unroll
                for (int t9 = 0; t9 < 9; ++t9) s2 += wq[j2 * 9 + t9] * xt[t9];
                v[j2] = (short)f2b(fmaxf(s2, 0.f));
            }
            *(s16x4*)(dA + p * STR + 8 * ((sl >> 1) ^ ((p >> 3) & 1)) + (sl & 1) * 4) = v;
        }
    };

    // cb0 conv1 weights (36 contiguous f32, 16B-aligned)
    {
        const float* wsrc = w1k + (sl * 4) * 9;
#pragma unroll
        for (int i2 = 0; i2 < 36; ++i2) wq[i2] = wsrc[i2];
        *(f32x4*)bq = *(const f32x4*)(b1k + sl * 4);
    }
    __syncthreads();                            // xs visible
    conv1_slab(As[0]);
    __syncthreads();

#pragma unroll
    for (int cb = 0; cb < 4; ++cb) {
        if (cb < 3) {                           // issue next slab's conv1 weights early
            const float* wsrc = w1k + ((cb + 1) * 32 + sl * 4) * 9;
#pragma unroll
            for (int i2 = 0; i2 < 36; ++i2) wq[i2] = wsrc[i2];
            *(f32x4*)bq = *(const f32x4*)(b1k + (cb + 1) * 32 + sl * 4);
        }
#pragma unroll
        for (int tap = 0; tap < 9; ++tap) {
            const int it = cb * 9 + tap;        // compile-time
            if (it + 2 < 36) {                  // 3-deep ring, prefetch distance 2
                const ushort* src = wb + (size_t)(it + 2) * 4096;
#pragma unroll
                for (int n = 0; n < 4; ++n)
                    breg[(it + 2) % 3][n] = *(const s16x8*)(src + n * 512);
            }
            const int ioff = (tap / 3) * 19 + (tap % 3);
            s16x8 a[3];
#pragma unroll
            for (int m = 0; m < 3; ++m) {
                int ip = ibase[m] + ioff;
                a[m] = *(const s16x8*)(&As[cb & 1][ip * STR + 8 * (g ^ ((ip >> 3) & 1))]);
            }
#pragma unroll
            for (int n = 0; n < 4; ++n)
#pragma unroll
                for (int m = 0; m < 3; ++m)
                    acc[m][n] = __builtin_amdgcn_mfma_f32_16x16x32_bf16(a[m], breg[it % 3][n], acc[m][n], 0, 0, 0);
        }
        if (cb < 3) conv1_slab(As[(cb + 1) & 1]);
        __syncthreads();
    }
    // epilogue: C/D map col=lane&15, row=(lane>>4)*4+r
#pragma unroll
    for (int n = 0; n < 4; ++n) {
        int cout = (ngrp * 4 + n) * 16 + l16;
        float bv = bias[k * 128 + cout];
#pragma unroll
        for (int m = 0; m < 3; ++m)
#pragma unroll
            for (int r = 0; r < 4; ++r) {
                int row = (mgrp * 3 + m) * 16 + g * 4 + r;
                if (row < OP) {
                    float v2 = fmaxf(acc[m][n][r] + bv, 0.f);
                    hout[((size_t)bkL * OP + row) * 128 + cout] = f2b(v2);
                }
            }
    }
}

// ============ MFMA conv, whole A in LDS (conv3/conv4) ============
// Stage full [IP][128] A once (batched reg loads -> one latency), ONE barrier,
// then 36 barrier-free taps. B 2-deep register ring. Stride 136 (16B-aligned, <=2-way).
template <int IH, int IW, int OH, int OW, int MW>
__global__ __launch_bounds__(256) void mfconv_k(
    const ushort* __restrict__ hin, const ushort* __restrict__ wt,
    const float* __restrict__ bias, ushort* __restrict__ hout) {
    constexpr int IP = IH * IW, OP = OH * OW, STR = 136;
    constexpr int NCH = IP * 16, NLD = (NCH + 255) / 256;
    __shared__ ushort As[IP * STR];
    const int bi = blockIdx.x;
    const int xcd = bi & 7, jj = bi >> 3;
    const int k = xcd * 3 + jj % 3, b = jj / 3;
    const int bkL = b * 24 + k;
    const int tid = threadIdx.x;
    const int w = tid >> 6, l = tid & 63, l16 = l & 15, g = l >> 4;
    const int mgrp = w >> 1, ngrp = w & 1;
    const ushort* hsrc = hin + (size_t)bkL * IP * 128;
    const ushort* wb = wt + (size_t)k * 36 * 4096 + ngrp * 2048 + g * 128 + l16 * 8;

    // batched A stage: all loads in flight together
    s16x8 rv[NLD];
#pragma unroll
    for (int i = 0; i < NLD; ++i) {
        int t = tid + i * 256;
        int tc = t < NCH ? t : 0;
        rv[i] = *(const s16x8*)(hsrc + (size_t)(tc >> 4) * 128 + (tc & 15) * 8);
    }
    s16x8 breg[2][4];
#pragma unroll
    for (int n = 0; n < 4; ++n) breg[0][n] = *(const s16x8*)(wb + n * 512);
#pragma unroll
    for (int n = 0; n < 4; ++n) breg[1][n] = *(const s16x8*)(wb + 4096 + n * 512);

    f32x4 acc[MW][4];
#pragma unroll
    for (int m = 0; m < MW; ++m)
#pragma unroll
        for (int n = 0; n < 4; ++n) acc[m][n] = (f32x4)0.f;

    int ibase[MW];
#pragma unroll
    for (int m = 0; m < MW; ++m) {
        int row = (mgrp * MW + m) * 16 + l16;
        row = row < OP ? row : OP - 1;
        int oy = row / OW, ox = row - oy * OW;
        ibase[m] = oy * IW + ox;
    }
#pragma unroll
    for (int i = 0; i < NLD; ++i) {
        int t = tid + i * 256;
        if (t < NCH) *(s16x8*)(As + (t >> 4) * STR + (t & 15) * 8) = rv[i];
    }
    __syncthreads();                            // the only barrier

#pragma unroll
    for (int cb = 0; cb < 4; ++cb)
#pragma unroll
        for (int tap = 0; tap < 9; ++tap) {
            const int it = cb * 9 + tap;
            if (it + 1 < 36) {
                const ushort* src = wb + (size_t)(it + 1) * 4096;
#pragma unroll
                for (int n = 0; n < 4; ++n)
                    breg[(it + 1) & 1][n] = *(const s16x8*)(src + n * 512);
            }
            const int ioff = (tap / 3) * IW + (tap % 3);
            s16x8 a[MW];
#pragma unroll
            for (int m = 0; m < MW; ++m)
                a[m] = *(const s16x8*)(As + (ibase[m] + ioff) * STR + cb * 32 + g * 8);
#pragma unroll
            for (int n = 0; n < 4; ++n)
#pragma unroll
                for (int m = 0; m < MW; ++m)
                    acc[m][n] = __builtin_amdgcn_mfma_f32_16x16x32_bf16(a[m], breg[it & 1][n], acc[m][n], 0, 0, 0);
        }
    // epilogue
#pragma unroll
    for (int n = 0; n < 4; ++n) {
        int cout = (ngrp * 4 + n) * 16 + l16;
        float bv = bias[k * 128 + cout];
#pragma unroll
        for (int m = 0; m < MW; ++m)
#pragma unroll
            for (int r = 0; r < 4; ++r) {
                int row = (mgrp * MW + m) * 16 + g * 4 + r;
                if (row < OP) {
                    float v2 = fmaxf(acc[m][n][r] + bv, 0.f);
                    hout[((size_t)bkL * OP + row) * 128 + cout] = f2b(v2);
                }
            }
    }
}

// ============ conv5 (1x1) + attention + pooling + heads + ocae assembly ============
__global__ __launch_bounds__(TPB) void head_k(const ushort* __restrict__ h4,
                                              const float* __restrict__ w5,
                                              const float* __restrict__ b5,
                                              const float* __restrict__ tpl,
                                              float* __restrict__ pose,
                                              float* __restrict__ dmv,
                                              float* __restrict__ out) {
    __shared__ float h4s[128 * 25];   // [c][pix]
    __shared__ float outs[16 * 25];   // [f][pix]
    __shared__ float atts[25];
    __shared__ float pooled[16];
    const int bk = blockIdx.x;
    const int k = bk % Kc;
    const ushort* hb = h4 + (size_t)bk * 25 * 128;
    for (int i = threadIdx.x; i < 25 * 128; i += TPB) {
        int pix = i >> 7, c = i & 127;
        h4s[c * 25 + pix] = b2f(hb[i]);
    }
    __syncthreads();
    for (int t = threadIdx.x; t < 400; t += TPB) {
        int f = t / 25, pix = t - f * 25;
        const float* wp = w5 + (size_t)(k * 16 + f) * 128;
        float s = b5[k * 16 + f];
        for (int c = 0; c < 128; ++c) s += wp[c] * h4s[c * 25 + pix];
        outs[t] = s;
    }
    __syncthreads();
    if (threadIdx.x < 25) {
        int y5 = threadIdx.x / 5;
        const float* row = outs + 15 * 25 + y5 * 5;
        float mx = row[0];
#pragma unroll
        for (int j = 1; j < 5; ++j) mx = fmaxf(mx, row[j]);
        float ssum = 0.f;
#pragma unroll
        for (int j = 0; j < 5; ++j) ssum += expf(row[j] - mx);
        atts[threadIdx.x] = expf(outs[15 * 25 + threadIdx.x] - mx) / ssum;
    }
    __syncthreads();
    if (threadIdx.x < 15) {
        float s = 0.f;
        const float* row = outs + threadIdx.x * 25;
#pragma unroll
        for (int p = 0; p < 25; ++p) s += row[p] * atts[p];
        pooled[threadIdx.x] = s;
    }
    __syncthreads();
    float* oc = out + OUT_OC + (size_t)bk * 136;
    if (threadIdx.x < 6) {
        float v = fmaxf(pooled[threadIdx.x], 0.f);
        pose[bk * 6 + threadIdx.x] = v;
        oc[1 + threadIdx.x] = v;
        out[OUT_XM + bk * 6 + threadIdx.x] = v;
    } else if (threadIdx.x == 6) {
        float d = 1.f / (1.f + expf(-pooled[6]));
        dmv[bk] = d;
        oc[0] = d;
        out[OUT_DM + bk] = d;
    } else if (threadIdx.x >= 7 && threadIdx.x < 15) {
        oc[128 + threadIdx.x - 7] = fmaxf(pooled[threadIdx.x], 0.f);
    }
    for (int t = threadIdx.x; t < 121; t += TPB) oc[7 + t] = tpl[k * 121 + t];
}

// ============ affine warp + bilinear TS->40x40, fused mix-softmax stats ============
__device__ __forceinline__ float tapf(const float* tp, int y, int x) {
    bool valid = (x >= 0) && (x < TSz) && (y >= 0) && (y < TSz);
    int yc = min(max(y, 0), TSz - 1), xc = min(max(x, 0), TSz - 1);
    float v = tp[yc * TSz + xc];
    return valid ? v : 0.f;
}

__global__ __launch_bounds__(TPB) void warp_mix_k(const float* __restrict__ pose,
                                                  const float* __restrict__ tpl,
                                                  const float* __restrict__ dmv,
                                                  float* __restrict__ tt,
                                                  float* __restrict__ mxs) {
    __shared__ float tp[121];
    const int bk = blockIdx.x, k = bk % Kc;
    for (int i = threadIdx.x; i < 121; i += TPB) tp[i] = tpl[k * 121 + i];
    const float* ps = pose + bk * 6;
    const float D2R = 0.017453292519943295f;
    float ang = ps[0] * D2R, tx = ps[1], ty = ps[2];
    float sc = fmaxf(ps[3], 1e-2f);
    float shx = ps[4] * D2R, shy = ps[5] * D2R;
    float cams = cosf(ang - shy), sams = sinf(ang - shy);
    float cshy = cosf(shy), tshx = tanf(shx);
    float av = cams / cshy;
    float bv = -cams * tshx / cshy - sinf(ang);
    float cv = sams / cshy;
    float dv = -sams * tshx / cshy + cosf(ang);
    float m0 = dv / sc, m1 = -bv / sc, m3 = -cv / sc, m4 = av / sc;
    float m2 = m0 * (-5.f - tx) + m1 * (-5.f - ty) + 5.f;
    float m5 = m3 * (-5.f - tx) + m4 * (-5.f - ty) + 5.f;
    __syncthreads();
    float* to = tt + (size_t)bk * 1600;
    float tvl[7];
#pragma unroll
    for (int r = 0; r < 7; ++r) {
        int p = threadIdx.x + r * TPB;
        float val = 0.f;
        if (p < 1600) {
            int i = p / 40, jx = p - (p / 40) * 40;
            float gx = (jx + 0.5f) * (11.f / 40.f) - 0.5f;
            float gy = (i + 0.5f) * (11.f / 40.f) - 0.5f;
            float xin = m0 * gx + m1 * gy + m2;
            float yin = m3 * gx + m4 * gy + m5;
            float x0 = floorf(xin), y0 = floorf(yin);
            float wx = xin - x0, wy = yin - y0;
            int x0i = (int)x0, y0i = (int)y0;
            float v00 = tapf(tp, y0i, x0i),     v01 = tapf(tp, y0i, x0i + 1);
            float v10 = tapf(tp, y0i + 1, x0i), v11 = tapf(tp, y0i + 1, x0i + 1);
            val = v00 * (1.f - wx) * (1.f - wy) + v01 * wx * (1.f - wy) +
                  v10 * (1.f - wx) * wy + v11 * wx * wy;
            to[p] = val;
        }
        tvl[r] = val;
    }
    const float dm = dmv[bk];
    float mx = -1e30f;
#pragma unroll
    for (int r = 0; r < 7; ++r) {
        int p = threadIdx.x + r * TPB;
        if (p < 1600) mx = fmaxf(mx, dm * tvl[r]);
    }
    mx = blockReduceMax(mx);
    float s = 0.f;
#pragma unroll
    for (int r = 0; r < 7; ++r) {
        int p = threadIdx.x + r * TPB;
        if (p < 1600) s += expf(dm * tvl[r] - mx);
    }
    s = blockReduceSum(s);
    if (threadIdx.x == 0) { mxs[bk * 2] = mx; mxs[bk * 2 + 1] = s; }
}

// ============ per-sample std stats ============
__global__ __launch_bounds__(TPB) void std_k(const float* __restrict__ x,
                                             float* __restrict__ st) {
    const int b = blockIdx.x;
    const float* xb = x + b * 1600;
    float s = 0.f, s2 = 0.f;
    for (int p = threadIdx.x; p < 1600; p += TPB) {
        float v = xb[p];
        s += v; s2 += v * v;
    }
    s = blockReduceSum(s);
    s2 = blockReduceSum(s2);
    if (threadIdx.x == 0) {
        float mean = s / 1600.f;
        float var = (s2 - 1600.f * mean * mean) / 1599.f;
        float sd = sqrtf(var);
        st[b * 2] = rsqrtf(sd * 6.283185307179586f);   // mult
        st[b * 2 + 1] = -1.f / (2.f * sd * sd);        // pw
    }
}

// ============ log-likelihood, split over 8 pixel-blocks per sample ============
__global__ __launch_bounds__(TPB) void ll_k(const float* __restrict__ x,
                                            const float* __restrict__ tt,
                                            const float* __restrict__ dmv,
                                            const float* __restrict__ mxs,
                                            const float* __restrict__ st,
                                            float* __restrict__ part) {
    const int b = blockIdx.x, sp = blockIdx.y;
    __shared__ float dms[24], mxh[24], sih[24];
    if (threadIdx.x < 24) {
        int bk = b * 24 + threadIdx.x;
        dms[threadIdx.x] = dmv[bk];
        mxh[threadIdx.x] = mxs[bk * 2];
        sih[threadIdx.x] = 1.f / mxs[bk * 2 + 1];
    }
    __syncthreads();
    const float mult = st[b * 2], pw = st[b * 2 + 1];
    const float* xb = x + b * 1600;
    const float* tb = tt + (size_t)b * 24 * 1600;
    float acc = 0.f;
    int p = sp * 200 + threadIdx.x;
    if (threadIdx.x < 200) {
        float xv = xb[p];
        float ssum = 0.f;
        for (int k = 0; k < 24; ++k) {
            float tv = tb[(size_t)k * 1600 + p];
            float dd = xv - tv;
            float g = mult * expf(dd * dd * pw);
            float mixv = expf(dms[k] * tv - mxh[k]) * sih[k];
            ssum += g * mixv;
        }
        acc = logf(ssum);
    }
    acc = blockReduceSum(acc);
    if (threadIdx.x == 0) part[b * 8 + sp] = acc;
}

__global__ void fin_k(const float* __restrict__ part, float* __restrict__ out) {
    float v = 0.f;
#pragma unroll
    for (int q = 0; q < 8; ++q) v += part[threadIdx.x * 8 + q];
#pragma unroll
    for (int o = 32; o > 0; o >>= 1) v += __shfl_down(v, o, 64);
    if (threadIdx.x == 0) out[0] = v * (1.f / 64.f);
}

// ============ launch ============
extern "C" void kernel_launch(void* const* d_in, const int* in_sizes, int n_in,
                              void* d_out, int out_size, void* d_ws, size_t ws_size,
                              hipStream_t stream) {
    const float* x   = (const float*)d_in[0];
    const float* w1  = (const float*)d_in[1];
    const float* b1  = (const float*)d_in[2];
    const float* w2  = (const float*)d_in[3];
    const float* b2  = (const float*)d_in[4];
    const float* w3  = (const float*)d_in[5];
    const float* b3  = (const float*)d_in[6];
    const float* w4  = (const float*)d_in[7];
    const float* b4  = (const float*)d_in[8];
    const float* w5  = (const float*)d_in[9];
    const float* b5  = (const float*)d_in[10];
    const float* tpl = (const float*)d_in[11];
    float* out = (float*)d_out;
    char* W = (char*)d_ws;

    ushort* wt2 = (ushort*)(W + OFFB_W2);
    ushort* wt3 = (ushort*)(W + OFFB_W3);
    ushort* wt4 = (ushort*)(W + OFFB_W4);
    ushort* h2u = (ushort*)(W + OFFB_H2);
    ushort* h3u = (ushort*)(W + OFFB_H3);
    ushort* h4u = (ushort*)(W + OFFB_H4);
    float*  pose = (float*)(W + OFFB_POSE);
    float*  dmv  = (float*)(W + OFFB_DMV);
    float*  ttb  = (float*)(W + OFFB_TT);
    float*  stv  = (float*)(W + OFFB_ST);
    float*  mxs  = (float*)(W + OFFB_MXS);
    float*  part = (float*)(W + OFFB_PART);

    wprep_k<<<Kc * 128, 128, 0, stream>>>(w2, wt2);
    wprep_k<<<Kc * 128, 128, 0, stream>>>(w3, wt3);
    wprep_k<<<Kc * 128, 128, 0, stream>>>(w4, wt4);
    std_k<<<Bn, TPB, 0, stream>>>(x, stv);

    conv12_k<<<NBK, 256, 0, stream>>>(x, w1, b1, wt2, b2, h2u);
    mfconv_k<9, 9, 7, 7, 2><<<NBK, 256, 0, stream>>>(h2u, wt3, b3, h3u);
    mfconv_k<7, 7, 5, 5, 1><<<NBK, 256, 0, stream>>>(h3u, wt4, b4, h4u);
    head_k<<<NBK, TPB, 0, stream>>>(h4u, w5, b5, tpl, pose, dmv, out);

    warp_mix_k<<<NBK, TPB, 0, stream>>>(pose, tpl, dmv, ttb, mxs);
    ll_k<<<dim3(Bn, 8), TPB, 0, stream>>>(x, ttb, dmv, mxs, stv, part);
    fin_k<<<1, 64, 0, stream>>>(part, out);
}